// Round 8
// baseline (9490.529 us; speedup 1.0000x reference)
//
#include <hip/hip_runtime.h>
#include <stdint.h>

typedef __attribute__((ext_vector_type(4))) float f32x4;
typedef __attribute__((ext_vector_type(8))) short short8;

#define VTH 1.0f
#define T_STEPS 64
#define DDIM 512
#define BM 32            // rows per workgroup
#define LDS_STRIDE 520   // 512 + 8 ushort pad
#define NWG 256
#define NTHREADS 1024    // 16 waves: wave ct owns cols [ct*32, ct*32+32)

// ws layout (ushort units): 6 x 512KB split matrices
#define OFF_WXH 0
#define OFF_WXM 262144
#define OFF_WXL 524288
#define OFF_WSH 786432
#define OFF_WSM 1048576
#define OFF_WSL 1310720

__device__ __forceinline__ unsigned short f32_to_bf16_rne(float f) {
    uint32_t u = __float_as_uint(f);
    uint32_t r = (u + 0x7FFFu + ((u >> 16) & 1u)) >> 16;
    return (unsigned short)r;
}
__device__ __forceinline__ float bf16_to_f32(unsigned short h) {
    return __uint_as_float(((uint32_t)h) << 16);
}

// 3-term split (exact to ~2^-25): w = H + M + L in bf16, fragment-linear layout.
// F(kb,nt,lane,slot) = ((kb*32+nt)*64 + lane)*8 + slot holds B[k][n] = W[n][k]
// with n = nt*16 + (lane&15), k = kb*32 + (lane>>4)*8 + slot.
__global__ void w_split3_kernel(const float* __restrict__ Wx, const float* __restrict__ Ws,
                                unsigned short* __restrict__ wsb) {
    int tid = blockIdx.x * blockDim.x + threadIdx.x;  // 0 .. 2*512*512-1
    int mat = tid >> 18;
    int rem = tid & 0x3FFFF;
    int n = rem >> 9, k = rem & 511;
    const float* W = mat ? Ws : Wx;
    unsigned short* H = wsb + (mat ? OFF_WSH : OFF_WXH);
    unsigned short* M = wsb + (mat ? OFF_WSM : OFF_WXM);
    unsigned short* L = wsb + (mat ? OFF_WSL : OFF_WXL);
    float w = W[n * DDIM + k];
    unsigned short hb = f32_to_bf16_rne(w);
    float r1 = w - bf16_to_f32(hb);          // exact (Sterbenz)
    unsigned short mb = f32_to_bf16_rne(r1);
    float r2 = r1 - bf16_to_f32(mb);         // exact
    unsigned short lb = f32_to_bf16_rne(r2);
    int kb = k >> 5, g = (k >> 3) & 3, slot = k & 7, nt = n >> 4, c16 = n & 15;
    int F = ((kb * 32 + nt) * 64 + (g * 16 + c16)) * 8 + slot;
    H[F] = hb;
    M[F] = mb;
    L[F] = lb;
}

// One K=512 single-term pass for one wave's 32-col slice:
// acc[2][2] (+)= A(32x512 in LDS) @ W(512 x 32 col-slice ct).
// Transient live set: Bb[2][2]=16 + a0/a1=8 VGPRs.
__device__ __forceinline__ void mfma_pass1(f32x4 (&acc)[2][2],
                                           const unsigned short* __restrict__ W,
                                           const unsigned short* slds,
                                           int ct, int lane) {
    const int g = lane >> 4, r = lane & 15;
    const int arow0 = r * LDS_STRIDE;
    const int arow1 = (16 + r) * LDS_STRIDE;
    short8 Bb[2][2];  // double-buffered B frags
    #pragma unroll
    for (int cf = 0; cf < 2; ++cf)
        Bb[0][cf] = *reinterpret_cast<const short8*>(W + ((ct * 2 + cf) * 64 + lane) * 8);
    #pragma unroll
    for (int kb = 0; kb < 16; ++kb) {
        const int cur = kb & 1, nxt = cur ^ 1;
        if (kb < 15) {
            #pragma unroll
            for (int cf = 0; cf < 2; ++cf)
                Bb[nxt][cf] = *reinterpret_cast<const short8*>(
                    W + (((kb + 1) * 32 + ct * 2 + cf) * 64 + lane) * 8);
        }
        const int aoff = kb * 32 + g * 8;
        short8 a0 = *reinterpret_cast<const short8*>(slds + arow0 + aoff);
        short8 a1 = *reinterpret_cast<const short8*>(slds + arow1 + aoff);
        #pragma unroll
        for (int cf = 0; cf < 2; ++cf) {
            acc[0][cf] = __builtin_amdgcn_mfma_f32_16x16x32_bf16(a0, Bb[cur][cf], acc[0][cf], 0, 0, 0);
            acc[1][cf] = __builtin_amdgcn_mfma_f32_16x16x32_bf16(a1, Bb[cur][cf], acc[1][cf], 0, 0, 0);
        }
    }
}

// Persistent per-row-block SNN kernel. 256 WGs x 1024 threads (16 waves);
// wave ct computes rows 0..31 x cols [ct*32, ct*32+32). Per-thread persistent
// state: acc 16 + cR 16 + packed spike counts 4 -> peak demand ~85 VGPRs < 128.
__global__ void __launch_bounds__(NTHREADS, 4)
snn_main_kernel(
    const float* __restrict__ x, const float* __restrict__ bs, const float* __restrict__ bx,
    const unsigned short* __restrict__ wsb, float* __restrict__ out) {
    __shared__ __align__(16) unsigned short slds[BM * LDS_STRIDE];
    const unsigned short* WxH = wsb + OFF_WXH;
    const unsigned short* WxM = wsb + OFF_WXM;
    const unsigned short* WxL = wsb + OFF_WXL;
    const unsigned short* WsH = wsb + OFF_WSH;
    const unsigned short* WsM = wsb + OFF_WSM;
    const unsigned short* WsL = wsb + OFF_WSL;
    const int tid = threadIdx.x;
    const int lane = tid & 63, ct = tid >> 6;   // ct = wave = col-tile 0..15
    const int g = lane >> 4, r = lane & 15;
    const int rowbase = blockIdx.x * BM;

    f32x4 acc[2][2];
    #pragma unroll
    for (int rf = 0; rf < 2; ++rf)
        #pragma unroll
        for (int cf = 0; cf < 2; ++cf) acc[rf][cf] = (f32x4){0.f, 0.f, 0.f, 0.f};

    // ---- phase 0: x1 = x @ Wx^T exact-to-fp32 via 3-term x and W splits.
    // Kept products: xh*(H,M,L) + xm*(H,M) + xl*H  (dropped terms <= x*w*2^-24)
    // pass A = xh  (1024 threads stage 2 rows per iteration)
    #pragma unroll 4
    for (int it = 0; it < BM / 2; ++it) {
        int row = it * 2 + (tid >> 9), col = tid & 511;
        float v = x[(rowbase + row) * DDIM + col];
        slds[row * LDS_STRIDE + col] = f32_to_bf16_rne(v);
    }
    __syncthreads();
    mfma_pass1(acc, WxH, slds, ct, lane);
    mfma_pass1(acc, WxM, slds, ct, lane);
    mfma_pass1(acc, WxL, slds, ct, lane);
    __syncthreads();
    // pass A = xm
    #pragma unroll 4
    for (int it = 0; it < BM / 2; ++it) {
        int row = it * 2 + (tid >> 9), col = tid & 511;
        float v = x[(rowbase + row) * DDIM + col];
        float h = bf16_to_f32(f32_to_bf16_rne(v));
        slds[row * LDS_STRIDE + col] = f32_to_bf16_rne(v - h);
    }
    __syncthreads();
    mfma_pass1(acc, WxH, slds, ct, lane);
    mfma_pass1(acc, WxM, slds, ct, lane);
    __syncthreads();
    // pass A = xl
    #pragma unroll 4
    for (int it = 0; it < BM / 2; ++it) {
        int row = it * 2 + (tid >> 9), col = tid & 511;
        float v = x[(rowbase + row) * DDIM + col];
        float h = bf16_to_f32(f32_to_bf16_rne(v));
        float m = bf16_to_f32(f32_to_bf16_rne(v - h));
        slds[row * LDS_STRIDE + col] = f32_to_bf16_rne(v - h - m);
    }
    __syncthreads();
    mfma_pass1(acc, WxH, slds, ct, lane);

    // ---- bias add; c = x1 + bs kept in registers (16 VGPRs) ----
    f32x4 cR[2][2];
    uint32_t aPk[2][2];  // packed spike counts: byte i = count of acc[rf][cf][i]
    #pragma unroll
    for (int cf = 0; cf < 2; ++cf) {
        int col = ct * 32 + cf * 16 + r;
        float bxv = bx[col];
        float bsv = bs[col];
        #pragma unroll
        for (int rf = 0; rf < 2; ++rf) {
            #pragma unroll
            for (int i = 0; i < 4; ++i) {
                acc[rf][cf][i] += bxv;
                cR[rf][cf][i] = acc[rf][cf][i] + bsv;
            }
            aPk[rf][cf] = 0u;
        }
    }

    // ---- time loop: spike -> (LDS) -> u += s@Ws^T + c ----
    #pragma unroll 1
    for (int t = 0; t < T_STEPS; ++t) {
        __syncthreads();  // previous step's A-fragment reads done before overwrite
        #pragma unroll
        for (int rf = 0; rf < 2; ++rf)
            #pragma unroll
            for (int cf = 0; cf < 2; ++cf)
                #pragma unroll
                for (int i = 0; i < 4; ++i) {
                    float u = acc[rf][cf][i];
                    bool sp = (u >= VTH);
                    acc[rf][cf][i] = u - (sp ? 1.0f : 0.0f);   // soft reset (vth = 1)
                    aPk[rf][cf] += sp ? (1u << (8 * i)) : 0u;  // packed count
                    int row = rf * 16 + g * 4 + i;             // C/D: row = (lane>>4)*4 + reg
                    int col = ct * 32 + cf * 16 + r;           // C/D: col = lane&15
                    slds[row * LDS_STRIDE + col] = sp ? (unsigned short)0x3F80 : (unsigned short)0;
                }
        if (t == T_STEPS - 1) break;
        __syncthreads();  // spike writes visible to all waves
        #pragma unroll
        for (int rf = 0; rf < 2; ++rf)
            #pragma unroll
            for (int cf = 0; cf < 2; ++cf)
                #pragma unroll
                for (int i = 0; i < 4; ++i)
                    acc[rf][cf][i] += cR[rf][cf][i];
        mfma_pass1(acc, WsH, slds, ct, lane);
        mfma_pass1(acc, WsM, slds, ct, lane);
        mfma_pass1(acc, WsL, slds, ct, lane);
    }

    // ---- output: a / 64 ----
    #pragma unroll
    for (int rf = 0; rf < 2; ++rf)
        #pragma unroll
        for (int cf = 0; cf < 2; ++cf)
            #pragma unroll
            for (int i = 0; i < 4; ++i) {
                int row = rf * 16 + g * 4 + i;
                int col = ct * 32 + cf * 16 + r;
                float cnt = (float)((aPk[rf][cf] >> (8 * i)) & 0xFFu);
                out[(rowbase + row) * DDIM + col] = cnt * (1.0f / 64.0f);
            }
}

extern "C" void kernel_launch(void* const* d_in, const int* in_sizes, int n_in,
                              void* d_out, int out_size, void* d_ws, size_t ws_size,
                              hipStream_t stream) {
    const float* x  = (const float*)d_in[0];
    const float* Ws = (const float*)d_in[1];
    const float* bs = (const float*)d_in[2];
    const float* Wx = (const float*)d_in[3];
    const float* bx = (const float*)d_in[4];
    float* out = (float*)d_out;

    unsigned short* wsb = (unsigned short*)d_ws;  // 3 MB: 6 x 512KB split matrices

    w_split3_kernel<<<2048, 256, 0, stream>>>(Wx, Ws, wsb);
    snn_main_kernel<<<NWG, NTHREADS, 0, stream>>>(x, bs, bx, wsb, out);
}

// Round 12
// 9065.616 us; speedup vs baseline: 1.0469x; 1.0469x over previous
//
#include <hip/hip_runtime.h>
#include <stdint.h>

typedef __attribute__((ext_vector_type(4))) float f32x4;
typedef __attribute__((ext_vector_type(8))) short short8;

#define VTH 1.0f
#define T_STEPS 64
#define DDIM 512
#define BM 32            // rows per workgroup
#define LDS_STRIDE 520   // 512 + 8 ushort pad
#define C_STRIDE 516     // f32 stride for c tile: 2-way bank aliasing only (free)
#define NWG 256
#define NTHREADS 1024    // 16 waves: wave ct owns cols [ct*32, ct*32+32)

// ws layout (ushort units): 6 x 512KB split matrices
#define OFF_WXH 0
#define OFF_WXM 262144
#define OFF_WXL 524288
#define OFF_WSH 786432
#define OFF_WSM 1048576
#define OFF_WSL 1310720

__device__ __forceinline__ unsigned short f32_to_bf16_rne(float f) {
    uint32_t u = __float_as_uint(f);
    uint32_t r = (u + 0x7FFFu + ((u >> 16) & 1u)) >> 16;
    return (unsigned short)r;
}
__device__ __forceinline__ float bf16_to_f32(unsigned short h) {
    return __uint_as_float(((uint32_t)h) << 16);
}

// 3-term split (exact to ~2^-25): w = H + M + L in bf16, fragment-linear layout.
// F(kb,nt,lane,slot) = ((kb*32+nt)*64 + lane)*8 + slot holds B[k][n] = W[n][k]
// with n = nt*16 + (lane&15), k = kb*32 + (lane>>4)*8 + slot.
__global__ void w_split3_kernel(const float* __restrict__ Wx, const float* __restrict__ Ws,
                                unsigned short* __restrict__ wsb) {
    int tid = blockIdx.x * blockDim.x + threadIdx.x;  // 0 .. 2*512*512-1
    int mat = tid >> 18;
    int rem = tid & 0x3FFFF;
    int n = rem >> 9, k = rem & 511;
    const float* W = mat ? Ws : Wx;
    unsigned short* H = wsb + (mat ? OFF_WSH : OFF_WXH);
    unsigned short* M = wsb + (mat ? OFF_WSM : OFF_WXM);
    unsigned short* L = wsb + (mat ? OFF_WSL : OFF_WXL);
    float w = W[n * DDIM + k];
    unsigned short hb = f32_to_bf16_rne(w);
    float r1 = w - bf16_to_f32(hb);          // exact (Sterbenz)
    unsigned short mb = f32_to_bf16_rne(r1);
    float r2 = r1 - bf16_to_f32(mb);         // exact
    unsigned short lb = f32_to_bf16_rne(r2);
    int kb = k >> 5, g = (k >> 3) & 3, slot = k & 7, nt = n >> 4, c16 = n & 15;
    int F = ((kb * 32 + nt) * 64 + (g * 16 + c16)) * 8 + slot;
    H[F] = hb;
    M[F] = mb;
    L[F] = lb;
}

// One K=512 single-term pass for one wave's 32-col slice:
// acc[2][2] (+)= A(32x512 in LDS) @ W(512 x 32 col-slice ct).
// Transient live set: Bb[2][2]=16 + a0/a1=8 VGPRs.
__device__ __forceinline__ void mfma_pass1(f32x4 (&acc)[2][2],
                                           const unsigned short* __restrict__ W,
                                           const unsigned short* slds,
                                           int ct, int lane) {
    const int g = lane >> 4, r = lane & 15;
    const int arow0 = r * LDS_STRIDE;
    const int arow1 = (16 + r) * LDS_STRIDE;
    short8 Bb[2][2];  // double-buffered B frags
    #pragma unroll
    for (int cf = 0; cf < 2; ++cf)
        Bb[0][cf] = *reinterpret_cast<const short8*>(W + ((ct * 2 + cf) * 64 + lane) * 8);
    #pragma unroll
    for (int kb = 0; kb < 16; ++kb) {
        const int cur = kb & 1, nxt = cur ^ 1;
        if (kb < 15) {
            #pragma unroll
            for (int cf = 0; cf < 2; ++cf)
                Bb[nxt][cf] = *reinterpret_cast<const short8*>(
                    W + (((kb + 1) * 32 + ct * 2 + cf) * 64 + lane) * 8);
        }
        const int aoff = kb * 32 + g * 8;
        short8 a0 = *reinterpret_cast<const short8*>(slds + arow0 + aoff);
        short8 a1 = *reinterpret_cast<const short8*>(slds + arow1 + aoff);
        #pragma unroll
        for (int cf = 0; cf < 2; ++cf) {
            acc[0][cf] = __builtin_amdgcn_mfma_f32_16x16x32_bf16(a0, Bb[cur][cf], acc[0][cf], 0, 0, 0);
            acc[1][cf] = __builtin_amdgcn_mfma_f32_16x16x32_bf16(a1, Bb[cur][cf], acc[1][cf], 0, 0, 0);
        }
    }
}

// Persistent per-row-block SNN kernel. 256 WGs x 1024 threads (16 waves);
// wave ct computes rows 0..31 x cols [ct*32, ct*32+32). Per-thread persistent
// state: acc 16 + packed counts 4; c = x1+bs in private LDS slots. Peak VGPR
// demand ~52 < 64 (worst allocator cap) -> no spill path. 99KB LDS -> 1 WG/CU.
__global__ void __launch_bounds__(NTHREADS)
snn_main_kernel(
    const float* __restrict__ x, const float* __restrict__ bs, const float* __restrict__ bx,
    const unsigned short* __restrict__ wsb, float* __restrict__ out) {
    __shared__ __align__(16) unsigned short slds[BM * LDS_STRIDE];
    __shared__ __align__(16) float c_lds[BM * C_STRIDE];
    const unsigned short* WxH = wsb + OFF_WXH;
    const unsigned short* WxM = wsb + OFF_WXM;
    const unsigned short* WxL = wsb + OFF_WXL;
    const unsigned short* WsH = wsb + OFF_WSH;
    const unsigned short* WsM = wsb + OFF_WSM;
    const unsigned short* WsL = wsb + OFF_WSL;
    const int tid = threadIdx.x;
    const int lane = tid & 63, ct = tid >> 6;   // ct = wave = col-tile 0..15
    const int g = lane >> 4, r = lane & 15;
    const int rowbase = blockIdx.x * BM;

    f32x4 acc[2][2];
    #pragma unroll
    for (int rf = 0; rf < 2; ++rf)
        #pragma unroll
        for (int cf = 0; cf < 2; ++cf) acc[rf][cf] = (f32x4){0.f, 0.f, 0.f, 0.f};

    // ---- phase 0: x1 = x @ Wx^T exact-to-fp32 via 3-term x and W splits.
    // Kept products: xh*(H,M,L) + xm*(H,M) + xl*H  (dropped terms <= x*w*2^-24)
    // pass A = xh  (1024 threads stage 2 rows per iteration)
    #pragma unroll 4
    for (int it = 0; it < BM / 2; ++it) {
        int row = it * 2 + (tid >> 9), col = tid & 511;
        float v = x[(rowbase + row) * DDIM + col];
        slds[row * LDS_STRIDE + col] = f32_to_bf16_rne(v);
    }
    __syncthreads();
    mfma_pass1(acc, WxH, slds, ct, lane);
    mfma_pass1(acc, WxM, slds, ct, lane);
    mfma_pass1(acc, WxL, slds, ct, lane);
    __syncthreads();
    // pass A = xm
    #pragma unroll 4
    for (int it = 0; it < BM / 2; ++it) {
        int row = it * 2 + (tid >> 9), col = tid & 511;
        float v = x[(rowbase + row) * DDIM + col];
        float h = bf16_to_f32(f32_to_bf16_rne(v));
        slds[row * LDS_STRIDE + col] = f32_to_bf16_rne(v - h);
    }
    __syncthreads();
    mfma_pass1(acc, WxH, slds, ct, lane);
    mfma_pass1(acc, WxM, slds, ct, lane);
    __syncthreads();
    // pass A = xl
    #pragma unroll 4
    for (int it = 0; it < BM / 2; ++it) {
        int row = it * 2 + (tid >> 9), col = tid & 511;
        float v = x[(rowbase + row) * DDIM + col];
        float h = bf16_to_f32(f32_to_bf16_rne(v));
        float m = bf16_to_f32(f32_to_bf16_rne(v - h));
        slds[row * LDS_STRIDE + col] = f32_to_bf16_rne(v - h - m);
    }
    __syncthreads();
    mfma_pass1(acc, WxH, slds, ct, lane);

    // ---- bias add; c = x1 + bs stored to per-thread-private LDS slots ----
    uint32_t aPk[2][2];  // packed spike counts: byte i = count of acc[rf][cf][i]
    #pragma unroll
    for (int cf = 0; cf < 2; ++cf) {
        int col = ct * 32 + cf * 16 + r;
        float bxv = bx[col];
        float bsv = bs[col];
        #pragma unroll
        for (int rf = 0; rf < 2; ++rf) {
            #pragma unroll
            for (int i = 0; i < 4; ++i) {
                int row = rf * 16 + g * 4 + i;
                acc[rf][cf][i] += bxv;
                c_lds[row * C_STRIDE + col] = acc[rf][cf][i] + bsv;
            }
            aPk[rf][cf] = 0u;
        }
    }

    // ---- time loop: spike -> (LDS) -> u += s@Ws^T + c ----
    #pragma unroll 1
    for (int t = 0; t < T_STEPS; ++t) {
        __syncthreads();  // previous step's A-fragment reads done before overwrite
        #pragma unroll
        for (int rf = 0; rf < 2; ++rf)
            #pragma unroll
            for (int cf = 0; cf < 2; ++cf)
                #pragma unroll
                for (int i = 0; i < 4; ++i) {
                    float u = acc[rf][cf][i];
                    bool sp = (u >= VTH);
                    acc[rf][cf][i] = u - (sp ? 1.0f : 0.0f);   // soft reset (vth = 1)
                    aPk[rf][cf] += sp ? (1u << (8 * i)) : 0u;  // packed count
                    int row = rf * 16 + g * 4 + i;             // C/D: row = (lane>>4)*4 + reg
                    int col = ct * 32 + cf * 16 + r;           // C/D: col = lane&15
                    slds[row * LDS_STRIDE + col] = sp ? (unsigned short)0x3F80 : (unsigned short)0;
                }
        if (t == T_STEPS - 1) break;
        __syncthreads();  // spike writes visible to all waves
        #pragma unroll
        for (int rf = 0; rf < 2; ++rf)
            #pragma unroll
            for (int cf = 0; cf < 2; ++cf)
                #pragma unroll
                for (int i = 0; i < 4; ++i) {
                    int row = rf * 16 + g * 4 + i;
                    int col = ct * 32 + cf * 16 + r;
                    acc[rf][cf][i] += c_lds[row * C_STRIDE + col];
                }
        mfma_pass1(acc, WsH, slds, ct, lane);
        mfma_pass1(acc, WsM, slds, ct, lane);
        mfma_pass1(acc, WsL, slds, ct, lane);
    }

    // ---- output: a / 64 ----
    #pragma unroll
    for (int rf = 0; rf < 2; ++rf)
        #pragma unroll
        for (int cf = 0; cf < 2; ++cf)
            #pragma unroll
            for (int i = 0; i < 4; ++i) {
                int row = rf * 16 + g * 4 + i;
                int col = ct * 32 + cf * 16 + r;
                float cnt = (float)((aPk[rf][cf] >> (8 * i)) & 0xFFu);
                out[(rowbase + row) * DDIM + col] = cnt * (1.0f / 64.0f);
            }
}

extern "C" void kernel_launch(void* const* d_in, const int* in_sizes, int n_in,
                              void* d_out, int out_size, void* d_ws, size_t ws_size,
                              hipStream_t stream) {
    const float* x  = (const float*)d_in[0];
    const float* Ws = (const float*)d_in[1];
    const float* bs = (const float*)d_in[2];
    const float* Wx = (const float*)d_in[3];
    const float* bx = (const float*)d_in[4];
    float* out = (float*)d_out;

    unsigned short* wsb = (unsigned short*)d_ws;  // 3 MB: 6 x 512KB split matrices

    w_split3_kernel<<<2048, 256, 0, stream>>>(Wx, Ws, wsb);
    snn_main_kernel<<<NWG, NTHREADS, 0, stream>>>(x, bs, bx, wsb, out);
}